// Round 4
// baseline (354.603 us; speedup 1.0000x reference)
//
#include <hip/hip_runtime.h>

// CTC forward loss, fused single kernel. B=64, T=2000, C=128 (blank=127),
// Lmax=200, S=401. Grid = 64 blocks x 256 threads.
//   wave 0   : serial alpha recursion (linear domain + per-lane pow2 exponent
//              tracking), 8 lattice positions/lane, 2 steps/round, reads
//              compact gathered probs from LDS (ds_read_b128, zero cvt).
//   waves 1-3: producers — softmax over C=128 + gather to label space:
//              G[t][l] = q(t, lab[l]) (fp32), blank at entry 200. Triple
//              buffered chunks of 24 rows; one __syncthreads per chunk.

#define LOG2E 1.44269504088896340736f
#define LN2F  0.69314718055994530942f

namespace {

constexpr int Bc = 64, Tc = 2000, Cc = 128, Lmaxc = 200;
constexpr int CH = 24;           // rows per chunk
constexpr int GROW = 832;        // G row stride bytes (200 f32 + blank@800 + pad)
constexpr int GBUF = CH * GROW;  // 19968 B per buffer

__global__ __launch_bounds__(256) void ctc_fused_kernel(
    const float* __restrict__ y, const int* __restrict__ y_true,
    const int* __restrict__ in_len, const int* __restrict__ lab_len,
    float* __restrict__ out) {
  __shared__ __align__(16) char G[3 * GBUF];   // 59904 B
  __shared__ float scratch[3 * 128];           // 1536 B (one exp-row per producer)
  const int b = blockIdx.x;
  const int tid = threadIdx.x;
  const int wid = tid >> 6, lane = tid & 63;
  int len = in_len[b];
  len = len < 1 ? 1 : (len > Tc ? Tc : len);
  const int ll = lab_len[b];
  const int* labs = y_true + b * Lmaxc;
  auto labc = [&](int l) -> int {
    int lc = l < 0 ? 0 : (l > Lmaxc - 1 ? Lmaxc - 1 : l);
    int c = labs[lc];
    return c < 0 ? 0 : c;  // ref maps padded -1 -> 0
  };

  const int NCg = (len + CH - 1) / CH;                          // chunks gathered
  const int cfull = len >= CH + 1 ? (len - (CH + 1)) / CH + 1 : 0;  // full chunks

  if (wid != 0) {
    // ------------------------- producers (waves 1..3) -------------------------
    const int j0 = wid - 1;
    const int cl0 = labc(lane), cl1 = labc(64 + lane), cl2 = labc(128 + lane);
    const int cl3 = labc(192 + lane);  // lanes 0..7 only
    float* myscr = scratch + j0 * 128;
    const float* yb = y + (size_t)b * Tc * Cc;

    auto fill = [&](int k) {
      if (k >= NCg) return;
      float2 ld[8];
#pragma unroll
      for (int i = 0; i < 8; ++i) {
        int r = CH * k + j0 + 3 * i;   // j0+3i <= 23 < CH, exact cover
        r = r > Tc - 1 ? Tc - 1 : r;
        ld[i] = *(const float2*)(yb + (size_t)r * Cc + lane * 2);
      }
      char* Gk = G + (k % 3) * GBUF;
#pragma unroll
      for (int i = 0; i < 8; ++i) {
        const int j = j0 + 3 * i;  // row within chunk
        float e0 = exp2f(fminf(ld[i].x * LOG2E, 50.f));
        float e1 = exp2f(fminf(ld[i].y * LOG2E, 50.f));
        float s = e0 + e1;
#pragma unroll
        for (int m = 1; m < 64; m <<= 1) s += __shfl_xor(s, m, 64);
        float rs = 1.0f / s;
        *(float2*)(myscr + lane * 2) = make_float2(e0, e1);
        float g0 = myscr[cl0], g1 = myscr[cl1], g2 = myscr[cl2];
        float* Gr = (float*)(Gk + j * GROW);
        Gr[lane] = g0 * rs;
        Gr[64 + lane] = g1 * rs;
        Gr[128 + lane] = g2 * rs;
        if (lane < 8) Gr[192 + lane] = myscr[cl3] * rs;
        if (lane == 8) Gr[200] = myscr[127] * rs;  // blank
      }
    };
    fill(0);
    fill(1);
    __syncthreads();
    for (int c = 0; c < cfull; ++c) {
      fill(c + 2);
      __syncthreads();
    }
    return;  // barrier counts match the consumer exactly
  }

  // --------------------------- consumer (wave 0) ----------------------------
  const int c0i = labc(4 * lane), c1i = labc(4 * lane + 1);
  const int c2i = labc(4 * lane + 2), c3i = labc(4 * lane + 3);
  const int cm1 = labc(4 * lane - 1), cm2 = labc(4 * lane - 2);
  const float sk0 = (4 * lane >= 1 && c0i != cm1) ? 1.f : 0.f;
  const float sk1 = (c1i != c0i) ? 1.f : 0.f;
  const float sk2 = (c2i != c1i) ? 1.f : 0.f;
  const float sk3 = (c3i != c2i) ? 1.f : 0.f;
  const float skH = (lane >= 1 && cm1 != cm2) ? 1.f : 0.f;
  const int lane16 = 16 * lane;
  int haloOff = lane16 - 4;
  haloOff = haloOff < 0 ? 0 : haloOff;  // lane 0: value unused (corr==0)

  float a[8];
#pragma unroll
  for (int j = 0; j < 8; ++j) a[j] = 0.0f;
  int E = 0;

  __syncthreads();  // G[0], G[1] published
  {                 // seed from G[0] row 0
    const float* G0 = (const float*)G;
    float qb0 = G0[200], l0 = G0[0];
    if (lane == 0) { a[0] = qb0; a[1] = l0; }
  }
  float s7d = __shfl_up(a[7], 1, 64);
  float s6d = __shfl_up(a[6], 1, 64);
  float s5d = __shfl_up(a[5], 1, 64);
  int epd = __shfl_up(E, 1, 64);

  float4 q4A[2], q4B[2];
  float qhal[2], qblA[2], qblB[2];
  {  // prefetch round 0 of chunk 0 (rows 1,2)
    q4A[0] = *(const float4*)(G + 1 * GROW + lane16);
    qhal[0] = *(const float*)(G + 1 * GROW + haloOff);
    qblA[0] = *(const float*)(G + 1 * GROW + 800);
    q4B[0] = *(const float4*)(G + 2 * GROW + lane16);
    qblB[0] = *(const float*)(G + 2 * GROW + 800);
  }

  for (int c = 0; c < cfull; ++c) {
    const char* GA = G + (c % 3) * GBUF;
    const char* GB = G + ((c + 1) % 3) * GBUF;
#pragma unroll
    for (int rr = 0; rr < 12; ++rr) {
      const int p = rr & 1, pn = p ^ 1;
      // prefetch the NEXT round's rows (compile-time offsets)
      const char* pA;
      const char* pB;
      int oA, oB;
      if (rr < 10) { pA = GA; oA = (3 + 2 * rr) * GROW; pB = GA; oB = (4 + 2 * rr) * GROW; }
      else if (rr == 10) { pA = GA; oA = 23 * GROW; pB = GB; oB = 0; }       // cross round
      else { pA = GB; oA = 1 * GROW; pB = GB; oB = 2 * GROW; }               // next chunk r0
      q4A[pn] = *(const float4*)(pA + oA + lane16);
      qhal[pn] = *(const float*)(pA + oA + haloOff);
      qblA[pn] = *(const float*)(pA + oA + 800);
      q4B[pn] = *(const float4*)(pB + oB + lane16);
      qblB[pn] = *(const float*)(pB + oB + 800);

      const float qbA = qblA[p], qbB = qblB[p];
      // step t: boundary-free parts first
      float n2 = (a[2] + a[1]) * qbA;
      float n3 = (a[3] + a[2] + sk1 * a[1]) * q4A[p].y;
      float n4 = (a[4] + a[3]) * qbA;
      float n5 = (a[5] + a[4] + sk2 * a[3]) * q4A[p].z;
      float n6 = (a[6] + a[5]) * qbA;
      float n7 = (a[7] + a[6] + sk3 * a[5]) * q4A[p].w;
      // step t+1: boundary-free parts
      float m4 = (n4 + n3) * qbB;
      float m5 = (n5 + n4 + sk2 * n3) * q4B[p].z;
      float m6 = (n6 + n5) * qbB;
      float m7 = (n7 + n6 + sk3 * n5) * q4B[p].w;
      // consume delayed neighbor boundary
      int de = epd - E;
      de = de < -126 ? -126 : (de > 60 ? 60 : de);
      float corr = __int_as_float((de + 127) << 23);
      corr = (lane == 0) ? 0.0f : corr;
      float w7 = s7d * corr, w6 = s6d * corr, w5 = s5d * corr;
      float hA = (w7 + w6 + skH * w5) * qhal[p];
      float n0 = (a[0] + w7) * qbA;
      float n1 = (a[1] + a[0] + sk0 * w7) * q4A[p].x;
      float m0 = (n0 + hA) * qbB;
      float m1 = (n1 + n0 + sk0 * hA) * q4B[p].x;
      float m2 = (n2 + n1) * qbB;
      float m3 = (n3 + n2 + sk1 * n1) * q4B[p].y;
      a[0] = m0; a[1] = m1; a[2] = m2; a[3] = m3;
      a[4] = m4; a[5] = m5; a[6] = m6; a[7] = m7;
      if ((rr & 3) == 3) {  // renorm every 8 steps (exact pow2)
        float mx = fmaxf(fmaxf(fmaxf(a[0], a[1]), fmaxf(a[2], a[3])),
                         fmaxf(fmaxf(a[4], a[5]), fmaxf(a[6], a[7])));
        unsigned bits = __float_as_uint(mx);
        bool z = (bits == 0u);
        int e = (int)(bits >> 23) - 127;
        float f = __uint_as_float((254u - (bits >> 23)) << 23);  // 2^-e
        f = z ? 1.0f : f;
#pragma unroll
        for (int j = 0; j < 8; ++j) a[j] *= f;
        E = z ? epd : (E + e);
      }
      s7d = __shfl_up(a[7], 1, 64);
      s6d = __shfl_up(a[6], 1, 64);
      s5d = __shfl_up(a[5], 1, 64);
      epd = __shfl_up(E, 1, 64);
    }
    __syncthreads();
  }

  // remainder: single-step rounds inside chunk `cfull`
  for (int t = CH * cfull + 1; t < len; ++t) {
    const char* GR = G + (cfull % 3) * GBUF + (t - CH * cfull) * GROW;
    float4 g = *(const float4*)(GR + lane16);
    float bl = *(const float*)(GR + 800);
    float s7 = __shfl_up(a[7], 1, 64);
    int ep = __shfl_up(E, 1, 64);
    int de = ep - E;
    de = de < -126 ? -126 : (de > 60 ? 60 : de);
    float corr = __int_as_float((de + 127) << 23);
    corr = (lane == 0) ? 0.0f : corr;
    float w7 = s7 * corr;
    float n0 = (a[0] + w7) * bl;
    float n1 = (a[1] + a[0] + sk0 * w7) * g.x;
    float n2 = (a[2] + a[1]) * bl;
    float n3 = (a[3] + a[2] + sk1 * a[1]) * g.y;
    float n4 = (a[4] + a[3]) * bl;
    float n5 = (a[5] + a[4] + sk2 * a[3]) * g.z;
    float n6 = (a[6] + a[5]) * bl;
    float n7 = (a[7] + a[6] + sk3 * a[5]) * g.w;
    a[0] = n0; a[1] = n1; a[2] = n2; a[3] = n3;
    a[4] = n4; a[5] = n5; a[6] = n6; a[7] = n7;
    if ((t & 7) == 0) {
      float mx = fmaxf(fmaxf(fmaxf(a[0], a[1]), fmaxf(a[2], a[3])),
                       fmaxf(fmaxf(a[4], a[5]), fmaxf(a[6], a[7])));
      unsigned bits = __float_as_uint(mx);
      bool z = (bits == 0u);
      int e = (int)(bits >> 23) - 127;
      float f = __uint_as_float((254u - (bits >> 23)) << 23);
      f = z ? 1.0f : f;
#pragma unroll
      for (int j = 0; j < 8; ++j) a[j] *= f;
      E = z ? ep : (E + e);
    }
  }

  // final combine: loss = -lse(alpha[2ll], alpha[2ll-1]) in log2 domain
  int sE = 2 * ll;
  int sP = sE - 1 < 0 ? 0 : sE - 1;
  int laneA = sE >> 3, jA = sE & 7;
  int laneB = sP >> 3, jB = sP & 7;
  float va = a[0];
  if (jA == 1) va = a[1];
  if (jA == 2) va = a[2];
  if (jA == 3) va = a[3];
  if (jA == 4) va = a[4];
  if (jA == 5) va = a[5];
  if (jA == 6) va = a[6];
  if (jA == 7) va = a[7];
  float vb = a[0];
  if (jB == 1) vb = a[1];
  if (jB == 2) vb = a[2];
  if (jB == 3) vb = a[3];
  if (jB == 4) vb = a[4];
  if (jB == 5) vb = a[5];
  if (jB == 6) vb = a[6];
  if (jB == 7) vb = a[7];
  float aA = __int_as_float(__builtin_amdgcn_ds_bpermute(laneA << 2, __float_as_int(va)));
  float aB = __int_as_float(__builtin_amdgcn_ds_bpermute(laneB << 2, __float_as_int(vb)));
  int EA = __builtin_amdgcn_ds_bpermute(laneA << 2, E);
  int EB = __builtin_amdgcn_ds_bpermute(laneB << 2, E);
  if (lane == 0) {
    float l1 = (aA > 0.0f) ? (float)EA + log2f(aA) : -1e30f;
    float l2 = (aB > 0.0f) ? (float)EB + log2f(aB) : -1e30f;
    float mm = fmaxf(l1, l2);
    float v = mm + log2f(exp2f(l1 - mm) + exp2f(l2 - mm));
    out[b] = -v * LN2F;
  }
}

}  // namespace

extern "C" void kernel_launch(void* const* d_in, const int* in_sizes, int n_in,
                              void* d_out, int out_size, void* d_ws, size_t ws_size,
                              hipStream_t stream) {
  const float* y = (const float*)d_in[0];   // [64,2000,128] f32
  const int* yt = (const int*)d_in[1];      // [64,200] i32
  const int* il = (const int*)d_in[2];      // [64] i32
  const int* lb = (const int*)d_in[3];      // [64] i32
  float* out = (float*)d_out;               // [64] f32
  (void)d_ws; (void)ws_size; (void)in_sizes; (void)n_in; (void)out_size;

  hipLaunchKernelGGL(ctc_fused_kernel, dim3(Bc), dim3(256), 0, stream,
                     y, yt, il, lb, out);
}